// Round 3
// baseline (493.907 us; speedup 1.0000x reference)
//
#include <hip/hip_runtime.h>
#include <cmath>

// ---------------------------------------------------------------------------
// GNNPooling: 3x (ChebConv -> BN(train) -> ReLU) -> mean over nodes.
// Lhat = alpha*I + beta*J  =>  y[b] = A_b @ WI + 1 * (colsum(A_b) @ WJ)
// GEMM via mfma_f32_16x16x32_bf16; A prefetched in fragment order from global
// (y stored pre-swizzled bf16 granules); W pre-swizzled into B-frag granules.
// ---------------------------------------------------------------------------

typedef __attribute__((ext_vector_type(8))) short bf16x8;
typedef __attribute__((ext_vector_type(4))) float f32x4;

constexpr int BATCH = 4096;
constexpr int DCH   = 128;
constexpr float INV_NROWS = 1.0f / 262144.0f;

// workspace offsets (in floats)
constexpr size_t OFF_GW1I = 0;            // 4096 granules * 16B = 16384 floats
constexpr size_t OFF_GW2I = 16384;        // 2048 granules -> 8192 floats
constexpr size_t OFF_GW3I = 24576;        // 8192 floats
constexpr size_t OFF_WJ1F = 32768;        // fp32 row-major 256x128
constexpr size_t OFF_WJ2F = 65536;        // 128x128
constexpr size_t OFF_WJ3F = 81920;        // 128x128
constexpr size_t OFF_RAW  = 98304;        // 3*256
constexpr size_t OFF_PART = 99072;        // 4096*256 floats
constexpr size_t OFF_Y    = 1147648;      // y bf16: 4096*64*128 ushorts

struct Coeffs { float a[5]; float b[5]; };

__device__ __forceinline__ unsigned short f2bf(float f) {
  unsigned u = __float_as_uint(f);
  u += 0x7FFFu + ((u >> 16) & 1u);        // round-to-nearest-even
  return (unsigned short)(u >> 16);
}
__device__ __forceinline__ float bf2f(unsigned short s) {
  return __uint_as_float(((unsigned)s) << 16);
}

// ---------------------------------------------------------------------------
// prep_gran: build WI (= sum_k a_k W_k) in B-fragment granule order, bf16.
// granule r = kt*512 + ct*64 + lane ; value_i = WI[kt*32+(lane>>4)*8+i][ct*16+(lane&15)]
// ---------------------------------------------------------------------------
__device__ __forceinline__ void gather8(const float* __restrict__ W, int CIN, int K,
                                        const float* cf, int f0, int col,
                                        unsigned short* dst) {
  bf16x8 g;
#pragma unroll
  for (int i = 0; i < 8; ++i) {
    float s = 0.f;
    if (K == 5) {
#pragma unroll
      for (int k = 0; k < 5; ++k)
        s = fmaf(cf[k], W[((size_t)k * CIN + f0 + i) * DCH + col], s);
    } else {
#pragma unroll
      for (int k = 0; k < 3; ++k)
        s = fmaf(cf[k], W[((size_t)k * CIN + f0 + i) * DCH + col], s);
    }
    g[i] = (short)f2bf(s);
  }
  *reinterpret_cast<bf16x8*>(dst) = g;
}

__global__ __launch_bounds__(256) void prep_gran(const float* __restrict__ W1,
                                                 const float* __restrict__ W2,
                                                 const float* __restrict__ W3,
                                                 float* __restrict__ ws, Coeffs co)
{
  int id = blockIdx.x * 256 + threadIdx.x;       // 0..8191
  const float* W; int CIN, K; unsigned short* dst; int r;
  if (id < 4096)      { W = W1; CIN = 256; K = 5; r = id;        dst = (unsigned short*)(ws + OFF_GW1I); }
  else if (id < 6144) { W = W2; CIN = 128; K = 3; r = id - 4096; dst = (unsigned short*)(ws + OFF_GW2I); }
  else                { W = W3; CIN = 128; K = 3; r = id - 6144; dst = (unsigned short*)(ws + OFF_GW3I); }
  int kt = r >> 9;
  int ct = (r >> 6) & 7;
  int ln = r & 63;
  int col = ct * 16 + (ln & 15);
  int f0  = kt * 32 + (ln >> 4) * 8;
  gather8(W, CIN, K, co.a, f0, col, dst + (size_t)r * 8);
}

// WJ in fp32 row-major (for the per-block J GEMV)
__global__ __launch_bounds__(256) void prep_wj(const float* __restrict__ W1,
                                               const float* __restrict__ W2,
                                               const float* __restrict__ W3,
                                               float* __restrict__ ws, Coeffs co)
{
  int id = blockIdx.x * 256 + threadIdx.x;       // 0..65535
  if (id < 32768) {
    int f = id >> 7, o = id & 127;
    float s = 0.f;
#pragma unroll
    for (int k = 0; k < 5; ++k) s = fmaf(co.b[k], W1[((size_t)k * 256 + f) * DCH + o], s);
    ws[OFF_WJ1F + id] = s;
  } else if (id < 49152) {
    int e = id - 32768, f = e >> 7, o = e & 127;
    float s = 0.f;
#pragma unroll
    for (int k = 0; k < 3; ++k) s = fmaf(co.b[k], W2[((size_t)k * 128 + f) * DCH + o], s);
    ws[OFF_WJ2F + e] = s;
  } else {
    int e = id - 49152, f = e >> 7, o = e & 127;
    float s = 0.f;
#pragma unroll
    for (int k = 0; k < 3; ++k) s = fmaf(co.b[k], W3[((size_t)k * 128 + f) * DCH + o], s);
    ws[OFF_WJ3F + e] = s;
  }
}

// ---------------------------------------------------------------------------
// Fused layer. Block = one batch (64 nodes x 128 outputs), 4 waves.
// Wave w owns rows w*16..w*16+15. MFMA 16x16x32 bf16, acc per wave: 8 n-tiles.
// A fully prefetched; kt loop fully unrolled.
// ---------------------------------------------------------------------------
template <int CIN, bool FIRST>
__global__ __launch_bounds__(256, 2) void layer_k(
    const float* __restrict__ inF,              // FIRST: x (row-major fp32)
    const unsigned short* __restrict__ inB,     // !FIRST: y bf16 granules
    unsigned short* __restrict__ yout,          // y bf16 granules
    const unsigned short* __restrict__ gWI,     // WI b-frag granules bf16
    const float* __restrict__ WJf,              // WJ fp32 row-major CIN x 128
    const float* __restrict__ raw, const float* __restrict__ gam,
    const float* __restrict__ bet, float* __restrict__ part)
{
  constexpr int NKT = CIN / 32;

  __shared__ float sS4[4][CIN];        // per-wave column-sum partials
  __shared__ float sJh[2][DCH];        // J GEMV halves
  __shared__ float sScale[DCH];
  __shared__ float sShift[DCH];
  __shared__ float sY[64][68];         // epilogue transpose / sRed union

  const int tid = threadIdx.x;
  const int w  = tid >> 6;
  const int l  = tid & 63;
  const int lr = l & 15;               // A-row within stripe / D-col within tile
  const int lk = l >> 4;               // k-slot
  const int b  = blockIdx.x;

  // ---------------- A prefetch: issue ALL global loads up front ----------------
  float4 araw0[FIRST ? NKT : 1], araw1[FIRST ? NKT : 1];
  bf16x8 abf[FIRST ? 1 : NKT];
  if constexpr (FIRST) {
    const float* ap = inF + ((size_t)(b * 64 + w * 16 + lr)) * CIN + lk * 8;
#pragma unroll
    for (int kt = 0; kt < NKT; ++kt) {
      araw0[kt] = *reinterpret_cast<const float4*>(ap + kt * 32);
      araw1[kt] = *reinterpret_cast<const float4*>(ap + kt * 32 + 4);
    }
  } else {
    const bf16x8* yp = reinterpret_cast<const bf16x8*>(inB + (size_t)b * 8192) + w * 64 + l;
#pragma unroll
    for (int kt = 0; kt < NKT; ++kt) abf[kt] = yp[kt * 256];
  }

  if constexpr (!FIRST) {
    if (tid < DCH) {
      float mu  = raw[tid] * INV_NROWS;
      float var = raw[DCH + tid] * INV_NROWS - mu * mu;
      float rs  = rsqrtf(var + 1e-5f);
      float sc  = gam[tid] * rs;
      sScale[tid] = sc;
      sShift[tid] = fmaf(-mu, sc, bet[tid]);
    }
    __syncthreads();
  }

  f32x4 acc[8];
#pragma unroll
  for (int ct = 0; ct < 8; ++ct)
#pragma unroll
    for (int r = 0; r < 4; ++r) acc[ct][r] = 0.f;

  const bf16x8* gwl = reinterpret_cast<const bf16x8*>(gWI) + l;

#pragma unroll
  for (int kt = 0; kt < NKT; ++kt) {
    float v[8];
    if constexpr (FIRST) {
      v[0] = araw0[kt].x; v[1] = araw0[kt].y; v[2] = araw0[kt].z; v[3] = araw0[kt].w;
      v[4] = araw1[kt].x; v[5] = araw1[kt].y; v[6] = araw1[kt].z; v[7] = araw1[kt].w;
    } else {
      const int base = kt * 32 + lk * 8;
      const float4 sc0 = *reinterpret_cast<const float4*>(&sScale[base]);
      const float4 sc1 = *reinterpret_cast<const float4*>(&sScale[base + 4]);
      const float4 sh0 = *reinterpret_cast<const float4*>(&sShift[base]);
      const float4 sh1 = *reinterpret_cast<const float4*>(&sShift[base + 4]);
      const float scv[8] = {sc0.x, sc0.y, sc0.z, sc0.w, sc1.x, sc1.y, sc1.z, sc1.w};
      const float shv[8] = {sh0.x, sh0.y, sh0.z, sh0.w, sh1.x, sh1.y, sh1.z, sh1.w};
#pragma unroll
      for (int i = 0; i < 8; ++i)
        v[i] = fmaxf(fmaf(bf2f((unsigned short)abf[kt][i]), scv[i], shv[i]), 0.f);
    }

    bf16x8 afrag;
#pragma unroll
    for (int i = 0; i < 8; ++i) afrag[i] = (short)f2bf(v[i]);

    // 8 MFMAs against pre-swizzled B granules (L2-resident)
    const bf16x8* gw = gwl + kt * 512;
#pragma unroll
    for (int ct = 0; ct < 8; ++ct) {
      bf16x8 bfrag = gw[ct * 64];
      acc[ct] = __builtin_amdgcn_mfma_f32_16x16x32_bf16(afrag, bfrag, acc[ct], 0, 0, 0);
    }

    // column sums over the wave's 16 rows: 4-stage butterfly; every lane ends
    // with the full sums for its own 8 features -> lr==0 lanes write float4s.
#pragma unroll
    for (int i = 0; i < 8; ++i) v[i] += __shfl_xor(v[i], 1, 16);
#pragma unroll
    for (int i = 0; i < 8; ++i) v[i] += __shfl_xor(v[i], 2, 16);
#pragma unroll
    for (int i = 0; i < 8; ++i) v[i] += __shfl_xor(v[i], 4, 16);
#pragma unroll
    for (int i = 0; i < 8; ++i) v[i] += __shfl_xor(v[i], 8, 16);
    if (lr == 0) {
      *reinterpret_cast<float4*>(&sS4[w][kt * 32 + lk * 8])     = make_float4(v[0], v[1], v[2], v[3]);
      *reinterpret_cast<float4*>(&sS4[w][kt * 32 + lk * 8 + 4]) = make_float4(v[4], v[5], v[6], v[7]);
    }
  }
  __syncthreads();

  // J GEMV: jrow[o] = sum_f s[f] * WJ[f][o]
  {
    const int o = tid & 127, half = tid >> 7;
    float j = 0.f;
#pragma unroll 4
    for (int f = half * (CIN / 2); f < (half + 1) * (CIN / 2); ++f) {
      float s = sS4[0][f] + sS4[1][f] + sS4[2][f] + sS4[3][f];
      j = fmaf(s, WJf[(size_t)f * DCH + o], j);
    }
    sJh[half][o] = j;
  }
  __syncthreads();

  // epilogue: add J, BN partials from regs, transpose via LDS (two column halves),
  // store bf16 granules for the next layer's fragment-order loads.
  float psum[8], psq[8];
#pragma unroll
  for (int ct = 0; ct < 8; ++ct) { psum[ct] = 0.f; psq[ct] = 0.f; }

#pragma unroll
  for (int cp = 0; cp < 2; ++cp) {
#pragma unroll
    for (int cc = 0; cc < 4; ++cc) {
      const int ct = cp * 4 + cc;
      const float jv = sJh[0][ct * 16 + lr] + sJh[1][ct * 16 + lr];
#pragma unroll
      for (int r = 0; r < 4; ++r) {
        float val = acc[ct][r] + jv;
        psum[ct] += val;
        psq[ct]  = fmaf(val, val, psq[ct]);
        sY[w * 16 + lk * 4 + r][cc * 16 + lr] = val;
      }
    }
    __syncthreads();
#pragma unroll
    for (int k2 = 0; k2 < 2; ++k2) {
      const float* pr = &sY[w * 16 + lr][k2 * 32 + lk * 8];
      float4 a0 = *reinterpret_cast<const float4*>(pr);
      float4 a1 = *reinterpret_cast<const float4*>(pr + 4);
      float vals[8] = {a0.x, a0.y, a0.z, a0.w, a1.x, a1.y, a1.z, a1.w};
      bf16x8 st;
#pragma unroll
      for (int i = 0; i < 8; ++i) st[i] = (short)f2bf(vals[i]);
      *(reinterpret_cast<bf16x8*>(yout + (size_t)b * 8192) +
        ((cp * 2 + k2) * 256 + w * 64 + l)) = st;
    }
    __syncthreads();
  }

  // BN partial reduction (union sRed over sY: 64*68 = 2*128*17 floats)
  float* sRedS = &sY[0][0];
  float* sRedQ = sRedS + 128 * 17;
#pragma unroll
  for (int ct = 0; ct < 8; ++ct) {
    sRedS[(ct * 16 + lr) * 17 + (w * 4 + lk)] = psum[ct];
    sRedQ[(ct * 16 + lr) * 17 + (w * 4 + lk)] = psq[ct];
  }
  __syncthreads();
  {
    const int c = tid & 127;
    const float* src = (tid >> 7) ? sRedQ : sRedS;
    float tot = 0.f;
#pragma unroll
    for (int p = 0; p < 16; ++p) tot += src[c * 17 + p];
    part[(size_t)b * 256 + tid] = tot;          // coalesced per block
  }
}

// ---------------------------------------------------------------------------
// Reduce partials: raw[j] = sum_b part[b][j].  16 blocks x 256 threads.
// ---------------------------------------------------------------------------
__global__ __launch_bounds__(256) void finalize_k(const float* __restrict__ part,
                                                  float* __restrict__ raw)
{
  __shared__ float red[16][17];
  const int g  = blockIdx.x;                 // channel group (16 channels)
  const int ji = threadIdx.x & 15;
  const int bi = threadIdx.x >> 4;
  const int j  = g * 16 + ji;
  float s = 0.f;
  for (int bb = bi; bb < BATCH; bb += 16)
    s += part[(size_t)bb * 256 + j];
  red[bi][ji] = s;
  __syncthreads();
  if (bi == 0) {
    float t = 0.f;
#pragma unroll
    for (int p = 0; p < 16; ++p) t += red[p][ji];
    raw[j] = t;
  }
}

// ---------------------------------------------------------------------------
// Final BN + ReLU + mean over nodes (reads bf16 granules)
// ---------------------------------------------------------------------------
__global__ __launch_bounds__(256) void pool_k(const unsigned short* __restrict__ y,
                                              const float* __restrict__ raw,
                                              const float* __restrict__ gam,
                                              const float* __restrict__ bet,
                                              float* __restrict__ out)
{
  __shared__ float sYp[64][132];
  __shared__ float sPool[2][DCH];
  const int b = blockIdx.x;
  const int t = threadIdx.x;
  const int wv = t >> 6, l = t & 63;
  const int row = wv * 16 + (l & 15);

#pragma unroll
  for (int kt = 0; kt < 4; ++kt) {
    bf16x8 r16 = *(reinterpret_cast<const bf16x8*>(y + (size_t)b * 8192) + (kt * 256 + t));
    const int feat = kt * 32 + (l >> 4) * 8;
    float4 f0, f1;
    f0.x = bf2f((unsigned short)r16[0]); f0.y = bf2f((unsigned short)r16[1]);
    f0.z = bf2f((unsigned short)r16[2]); f0.w = bf2f((unsigned short)r16[3]);
    f1.x = bf2f((unsigned short)r16[4]); f1.y = bf2f((unsigned short)r16[5]);
    f1.z = bf2f((unsigned short)r16[6]); f1.w = bf2f((unsigned short)r16[7]);
    *reinterpret_cast<float4*>(&sYp[row][feat])     = f0;
    *reinterpret_cast<float4*>(&sYp[row][feat + 4]) = f1;
  }
  __syncthreads();
  {
    const int c = t & 127, rg = t >> 7;
    float mu  = raw[c] * INV_NROWS;
    float var = raw[DCH + c] * INV_NROWS - mu * mu;
    float rs  = rsqrtf(var + 1e-5f);
    float sc  = gam[c] * rs;
    float sh  = fmaf(-mu, sc, bet[c]);
    float s = 0.f;
#pragma unroll 8
    for (int r = rg * 32; r < rg * 32 + 32; ++r)
      s += fmaxf(fmaf(sYp[r][c], sc, sh), 0.f);
    sPool[rg][c] = s;
  }
  __syncthreads();
  if (t < DCH)
    out[(size_t)b * DCH + t] = (sPool[0][t] + sPool[1][t]) * (1.0f / 64.0f);
}

// ---------------------------------------------------------------------------
extern "C" void kernel_launch(void* const* d_in, const int* in_sizes, int n_in,
                              void* d_out, int out_size, void* d_ws, size_t ws_size,
                              hipStream_t stream)
{
  const float* x  = (const float*)d_in[0];
  const float* W1 = (const float*)d_in[1];
  const float* W2 = (const float*)d_in[2];
  const float* W3 = (const float*)d_in[3];
  const float* g1 = (const float*)d_in[4];
  const float* b1 = (const float*)d_in[5];
  const float* g2 = (const float*)d_in[6];
  const float* b2 = (const float*)d_in[7];
  const float* g3 = (const float*)d_in[8];
  const float* b3 = (const float*)d_in[9];
  float* out = (float*)d_out;
  float* ws  = (float*)d_ws;

  Coeffs co;
  {
    double sd  = sqrt(63.0 / 4095.0);
    double av  = exp(-1.0 / sd);
    double deg = 1.0 + 63.0 * av;
    double al  = -(1.0 - av) / deg;
    double be  = -av / deg;
    double ak[5], bk[5];
    ak[0] = 1.0; bk[0] = 0.0;
    ak[1] = al;  bk[1] = be;
    for (int k = 2; k < 5; ++k) {
      ak[k] = 2.0 * al * ak[k - 1] - ak[k - 2];
      bk[k] = 2.0 * (be * ak[k - 1] + (al + 64.0 * be) * bk[k - 1]) - bk[k - 2];
    }
    for (int k = 0; k < 5; ++k) { co.a[k] = (float)ak[k]; co.b[k] = (float)bk[k]; }
  }

  const unsigned short* gw1 = (const unsigned short*)(ws + OFF_GW1I);
  const unsigned short* gw2 = (const unsigned short*)(ws + OFF_GW2I);
  const unsigned short* gw3 = (const unsigned short*)(ws + OFF_GW3I);
  const float* wj1 = ws + OFF_WJ1F;
  const float* wj2 = ws + OFF_WJ2F;
  const float* wj3 = ws + OFF_WJ3F;
  float* raw1 = ws + OFF_RAW;
  float* raw2 = raw1 + 256;
  float* raw3 = raw1 + 512;
  float* pp   = ws + OFF_PART;
  unsigned short* yv = (unsigned short*)(ws + OFF_Y);

  prep_gran<<<32, 256, 0, stream>>>(W1, W2, W3, ws, co);
  prep_wj<<<256, 256, 0, stream>>>(W1, W2, W3, ws, co);

  layer_k<256, true ><<<BATCH, 256, 0, stream>>>(x, nullptr, yv, gw1, wj1,
                                                 nullptr, nullptr, nullptr, pp);
  finalize_k<<<16, 256, 0, stream>>>(pp, raw1);
  layer_k<128, false><<<BATCH, 256, 0, stream>>>(nullptr, yv, yv, gw2, wj2,
                                                 raw1, g1, b1, pp);
  finalize_k<<<16, 256, 0, stream>>>(pp, raw2);
  layer_k<128, false><<<BATCH, 256, 0, stream>>>(nullptr, yv, yv, gw3, wj3,
                                                 raw2, g2, b2, pp);
  finalize_k<<<16, 256, 0, stream>>>(pp, raw3);
  pool_k<<<BATCH, 256, 0, stream>>>(yv, raw3, g3, b3, out);

  (void)in_sizes; (void)n_in; (void)out_size; (void)ws_size;
}

// Round 4
// 305.829 us; speedup vs baseline: 1.6150x; 1.6150x over previous
//
#include <hip/hip_runtime.h>
#include <cmath>

// ---------------------------------------------------------------------------
// GNNPooling: 3x (ChebConv -> BN(train) -> ReLU) -> mean over nodes.
// Lhat = alpha*I + beta*J  =>  y[b] = A_b @ WI + 1 * colsum(A_b @ WJ)
// (colsum(A)@WJ == colsum(A@WJ) -> J-term via 8 extra MFMAs, no shuffles/GEMV)
// GEMM via mfma_f32_16x16x32_bf16; A loaded in fragment order from global
// (y stored pre-swizzled bf16 granules); WI,WJ pre-swizzled B-frag granules.
// ---------------------------------------------------------------------------

typedef __attribute__((ext_vector_type(8))) short bf16x8;
typedef __attribute__((ext_vector_type(4))) float f32x4;

constexpr int BATCH = 4096;
constexpr int DCH   = 128;
constexpr float INV_NROWS = 1.0f / 262144.0f;

// workspace offsets (in floats)
constexpr size_t OFF_G1   = 0;            // layer1 WI+WJ granules: 8192*8 bf16 = 32768 floats
constexpr size_t OFF_G2   = 32768;        // layer2: 4096*8 bf16 = 16384 floats
constexpr size_t OFF_G3   = 49152;        // layer3: 16384 floats
constexpr size_t OFF_RAW  = 65536;        // 3*256
constexpr size_t OFF_PP2  = 66304;        // 256*256 stage-A partials
constexpr size_t OFF_PART = 131840;       // 4096*256
constexpr size_t OFF_Y    = 1180416;      // y bf16: 4096*64*128 ushorts

struct Coeffs { float a[5]; float b[5]; };

__device__ __forceinline__ unsigned short f2bf(float f) {
  unsigned u = __float_as_uint(f);
  u += 0x7FFFu + ((u >> 16) & 1u);        // round-to-nearest-even
  return (unsigned short)(u >> 16);
}
__device__ __forceinline__ float bf2f(unsigned short s) {
  return __uint_as_float(((unsigned)s) << 16);
}

// ---------------------------------------------------------------------------
// prep_gran: build WI (= sum_k a_k W_k) and WJ (= sum_k b_k W_k) in
// B-fragment granule order, bf16.  granule r = kt*512 + ct*64 + lane;
// value_i = W[kt*32+(lane>>4)*8+i][ct*16+(lane&15)]
// ---------------------------------------------------------------------------
__global__ __launch_bounds__(256) void prep_gran(const float* __restrict__ W1,
                                                 const float* __restrict__ W2,
                                                 const float* __restrict__ W3,
                                                 float* __restrict__ ws, Coeffs co)
{
  int id = blockIdx.x * 256 + threadIdx.x;       // 0..16383
  const float* W; int CIN, K, r; const float* cf; unsigned short* dst;
  if (id < 8192) {
    W = W1; CIN = 256; K = 5; r = id & 4095;
    cf = (id >= 4096) ? co.b : co.a;
    dst = (unsigned short*)(ws + OFF_G1) + (size_t)id * 8;
  } else if (id < 12288) {
    int e = id - 8192; W = W2; CIN = 128; K = 3; r = e & 2047;
    cf = (e >= 2048) ? co.b : co.a;
    dst = (unsigned short*)(ws + OFF_G2) + (size_t)e * 8;
  } else {
    int e = id - 12288; W = W3; CIN = 128; K = 3; r = e & 2047;
    cf = (e >= 2048) ? co.b : co.a;
    dst = (unsigned short*)(ws + OFF_G3) + (size_t)e * 8;
  }
  int kt  = r >> 9;
  int ct  = (r >> 6) & 7;
  int ln  = r & 63;
  int col = ct * 16 + (ln & 15);
  int f0  = kt * 32 + (ln >> 4) * 8;
  bf16x8 g;
#pragma unroll
  for (int i = 0; i < 8; ++i) {
    float s = 0.f;
    for (int k = 0; k < K; ++k)
      s = fmaf(cf[k], W[((size_t)k * CIN + f0 + i) * DCH + col], s);
    g[i] = (short)f2bf(s);
  }
  *reinterpret_cast<bf16x8*>(dst) = g;
}

// ---------------------------------------------------------------------------
// Fused layer. Block = one batch (64 nodes x 128 outputs), 4 waves.
// Wave w owns rows w*16..w*16+15. Per kt: 8 MFMA (WI) + 8 MFMA (WJ).
// ---------------------------------------------------------------------------
template <int CIN, bool FIRST>
__global__ __launch_bounds__(256) void layer_k(
    const float* __restrict__ inF,              // FIRST: x (row-major fp32)
    const unsigned short* __restrict__ inB,     // !FIRST: y bf16 granules
    unsigned short* __restrict__ yout,          // y bf16 granules
    const unsigned short* __restrict__ gran,    // WI then WJ b-frag granules bf16
    const float* __restrict__ raw, const float* __restrict__ gam,
    const float* __restrict__ bet, float* __restrict__ part)
{
  constexpr int NKT = CIN / 32;
  constexpr int GWJ = CIN * 16;                 // granule offset of WJ region

  __shared__ float sJw[4][DCH];                 // per-wave colsums of T
  __shared__ float sScale[DCH];
  __shared__ float sShift[DCH];
  __shared__ float sY[64][132];                 // transpose buffer / sRed union

  const int tid = threadIdx.x;
  const int w  = tid >> 6;
  const int l  = tid & 63;
  const int lr = l & 15;               // A-row within stripe / D-col within tile
  const int lk = l >> 4;               // k-slot / D-row group
  const int b  = blockIdx.x;

  if constexpr (!FIRST) {
    if (tid < DCH) {
      float mu  = raw[tid] * INV_NROWS;
      float var = raw[DCH + tid] * INV_NROWS - mu * mu;
      float rs  = rsqrtf(var + 1e-5f);
      float sc  = gam[tid] * rs;
      sScale[tid] = sc;
      sShift[tid] = fmaf(-mu, sc, bet[tid]);
    }
    __syncthreads();
  }

  f32x4 accI[8], accJ[8];
#pragma unroll
  for (int ct = 0; ct < 8; ++ct)
#pragma unroll
    for (int r = 0; r < 4; ++r) { accI[ct][r] = 0.f; accJ[ct][r] = 0.f; }

  const bf16x8* gbase = reinterpret_cast<const bf16x8*>(gran) + l;

#pragma unroll
  for (int kt = 0; kt < NKT; ++kt) {
    bf16x8 afrag;
    if constexpr (FIRST) {
      const float* p = inF + ((size_t)(b * 64 + w * 16 + lr)) * CIN + kt * 32 + lk * 8;
      float4 u0 = *reinterpret_cast<const float4*>(p);
      float4 u1 = *reinterpret_cast<const float4*>(p + 4);
      afrag[0] = (short)f2bf(u0.x); afrag[1] = (short)f2bf(u0.y);
      afrag[2] = (short)f2bf(u0.z); afrag[3] = (short)f2bf(u0.w);
      afrag[4] = (short)f2bf(u1.x); afrag[5] = (short)f2bf(u1.y);
      afrag[6] = (short)f2bf(u1.z); afrag[7] = (short)f2bf(u1.w);
    } else {
      bf16x8 r16 = *(reinterpret_cast<const bf16x8*>(inB + (size_t)b * 8192) +
                     (kt * 256 + w * 64 + l));
      const int base = kt * 32 + lk * 8;
      const float4 sc0 = *reinterpret_cast<const float4*>(&sScale[base]);
      const float4 sc1 = *reinterpret_cast<const float4*>(&sScale[base + 4]);
      const float4 sh0 = *reinterpret_cast<const float4*>(&sShift[base]);
      const float4 sh1 = *reinterpret_cast<const float4*>(&sShift[base + 4]);
      const float scv[8] = {sc0.x, sc0.y, sc0.z, sc0.w, sc1.x, sc1.y, sc1.z, sc1.w};
      const float shv[8] = {sh0.x, sh0.y, sh0.z, sh0.w, sh1.x, sh1.y, sh1.z, sh1.w};
#pragma unroll
      for (int i = 0; i < 8; ++i)
        afrag[i] = (short)f2bf(
            fmaxf(fmaf(bf2f((unsigned short)r16[i]), scv[i], shv[i]), 0.f));
    }

    const bf16x8* gI = gbase + kt * 512;
    const bf16x8* gJ = gbase + GWJ + kt * 512;
#pragma unroll
    for (int ct = 0; ct < 8; ++ct) {
      accI[ct] = __builtin_amdgcn_mfma_f32_16x16x32_bf16(afrag, gI[ct * 64], accI[ct], 0, 0, 0);
      accJ[ct] = __builtin_amdgcn_mfma_f32_16x16x32_bf16(afrag, gJ[ct * 64], accJ[ct], 0, 0, 0);
    }
  }

  // column-reduce T = A@WJ: once per block (2 shuffles per ct)
#pragma unroll
  for (int ct = 0; ct < 8; ++ct) {
    float t = (accJ[ct][0] + accJ[ct][1]) + (accJ[ct][2] + accJ[ct][3]);
    t += __shfl_xor(t, 16);
    t += __shfl_xor(t, 32);
    if (lk == 0) sJw[w][ct * 16 + lr] = t;
  }
  __syncthreads();

  float jv[8];
#pragma unroll
  for (int ct = 0; ct < 8; ++ct)
    jv[ct] = (sJw[0][ct * 16 + lr] + sJw[1][ct * 16 + lr]) +
             (sJw[2][ct * 16 + lr] + sJw[3][ct * 16 + lr]);

  // epilogue: val = accI + jv -> sY (single phase), BN partials in regs
  float psum[8], psq[8];
#pragma unroll
  for (int ct = 0; ct < 8; ++ct) {
    psum[ct] = 0.f; psq[ct] = 0.f;
#pragma unroll
    for (int r = 0; r < 4; ++r) {
      float val = accI[ct][r] + jv[ct];
      psum[ct] += val;
      psq[ct]  = fmaf(val, val, psq[ct]);
      sY[w * 16 + lk * 4 + r][ct * 16 + lr] = val;
    }
  }
  __syncthreads();

  // y granule store: thread (w,l) emits granule k2*256 + w*64 + l
#pragma unroll
  for (int k2 = 0; k2 < 4; ++k2) {
    const float* pr = &sY[w * 16 + lr][k2 * 32 + lk * 8];
    float4 a0 = *reinterpret_cast<const float4*>(pr);
    float4 a1 = *reinterpret_cast<const float4*>(pr + 4);
    bf16x8 st;
    st[0] = (short)f2bf(a0.x); st[1] = (short)f2bf(a0.y);
    st[2] = (short)f2bf(a0.z); st[3] = (short)f2bf(a0.w);
    st[4] = (short)f2bf(a1.x); st[5] = (short)f2bf(a1.y);
    st[6] = (short)f2bf(a1.z); st[7] = (short)f2bf(a1.w);
    *(reinterpret_cast<bf16x8*>(yout + (size_t)b * 8192) + (k2 * 256 + w * 64 + l)) = st;
  }
  __syncthreads();                              // before reusing sY as sRed

  // BN partial reduction (reuse sY: needs 2*128*17 = 4352 floats <= 64*132)
  float* sRedS = &sY[0][0];
  float* sRedQ = sRedS + 128 * 17;
#pragma unroll
  for (int ct = 0; ct < 8; ++ct) {
    sRedS[(ct * 16 + lr) * 17 + (w * 4 + lk)] = psum[ct];
    sRedQ[(ct * 16 + lr) * 17 + (w * 4 + lk)] = psq[ct];
  }
  __syncthreads();
  {
    const int c = tid & 127;
    const float* src = (tid >> 7) ? sRedQ : sRedS;
    float tot = 0.f;
#pragma unroll
    for (int p = 0; p < 16; ++p) tot += src[c * 17 + p];
    part[(size_t)b * 256 + tid] = tot;          // coalesced per block
  }
}

// ---------------------------------------------------------------------------
// Two-stage fully-coalesced reduction of part[4096][256] -> raw[256]
// ---------------------------------------------------------------------------
__global__ __launch_bounds__(256) void finA_k(const float* __restrict__ part,
                                              float* __restrict__ pp2)
{
  const int g = blockIdx.x;                     // 0..255, rows g*16..g*16+15
  float s = 0.f;
#pragma unroll
  for (int i = 0; i < 16; ++i)
    s += part[(size_t)(g * 16 + i) * 256 + threadIdx.x];
  pp2[(size_t)g * 256 + threadIdx.x] = s;
}

__global__ __launch_bounds__(1024) void finB_k(const float* __restrict__ pp2,
                                               float* __restrict__ raw)
{
  __shared__ float red[4][256];
  const int q = threadIdx.x >> 8, t = threadIdx.x & 255;
  float s = 0.f;
#pragma unroll 8
  for (int i = 0; i < 64; ++i)
    s += pp2[(size_t)(q * 64 + i) * 256 + t];
  red[q][t] = s;
  __syncthreads();
  if (q == 0) raw[t] = (red[0][t] + red[1][t]) + (red[2][t] + red[3][t]);
}

// ---------------------------------------------------------------------------
// Final BN + ReLU + mean over nodes (reads bf16 granules)
// ---------------------------------------------------------------------------
__global__ __launch_bounds__(256) void pool_k(const unsigned short* __restrict__ y,
                                              const float* __restrict__ raw,
                                              const float* __restrict__ gam,
                                              const float* __restrict__ bet,
                                              float* __restrict__ out)
{
  __shared__ float sYp[64][132];
  __shared__ float sPool[2][DCH];
  const int b = blockIdx.x;
  const int t = threadIdx.x;
  const int wv = t >> 6, l = t & 63;
  const int row = wv * 16 + (l & 15);

#pragma unroll
  for (int kt = 0; kt < 4; ++kt) {
    bf16x8 r16 = *(reinterpret_cast<const bf16x8*>(y + (size_t)b * 8192) + (kt * 256 + t));
    const int feat = kt * 32 + (l >> 4) * 8;
    float4 f0, f1;
    f0.x = bf2f((unsigned short)r16[0]); f0.y = bf2f((unsigned short)r16[1]);
    f0.z = bf2f((unsigned short)r16[2]); f0.w = bf2f((unsigned short)r16[3]);
    f1.x = bf2f((unsigned short)r16[4]); f1.y = bf2f((unsigned short)r16[5]);
    f1.z = bf2f((unsigned short)r16[6]); f1.w = bf2f((unsigned short)r16[7]);
    *reinterpret_cast<float4*>(&sYp[row][feat])     = f0;
    *reinterpret_cast<float4*>(&sYp[row][feat + 4]) = f1;
  }
  __syncthreads();
  {
    const int c = t & 127, rg = t >> 7;
    float mu  = raw[c] * INV_NROWS;
    float var = raw[DCH + c] * INV_NROWS - mu * mu;
    float rs  = rsqrtf(var + 1e-5f);
    float sc  = gam[c] * rs;
    float sh  = fmaf(-mu, sc, bet[c]);
    float s = 0.f;
#pragma unroll 8
    for (int r = rg * 32; r < rg * 32 + 32; ++r)
      s += fmaxf(fmaf(sYp[r][c], sc, sh), 0.f);
    sPool[rg][c] = s;
  }
  __syncthreads();
  if (t < DCH)
    out[(size_t)b * DCH + t] = (sPool[0][t] + sPool[1][t]) * (1.0f / 64.0f);
}

// ---------------------------------------------------------------------------
extern "C" void kernel_launch(void* const* d_in, const int* in_sizes, int n_in,
                              void* d_out, int out_size, void* d_ws, size_t ws_size,
                              hipStream_t stream)
{
  const float* x  = (const float*)d_in[0];
  const float* W1 = (const float*)d_in[1];
  const float* W2 = (const float*)d_in[2];
  const float* W3 = (const float*)d_in[3];
  const float* g1 = (const float*)d_in[4];
  const float* b1 = (const float*)d_in[5];
  const float* g2 = (const float*)d_in[6];
  const float* b2 = (const float*)d_in[7];
  const float* g3 = (const float*)d_in[8];
  const float* b3 = (const float*)d_in[9];
  float* out = (float*)d_out;
  float* ws  = (float*)d_ws;

  Coeffs co;
  {
    double sd  = sqrt(63.0 / 4095.0);
    double av  = exp(-1.0 / sd);
    double deg = 1.0 + 63.0 * av;
    double al  = -(1.0 - av) / deg;
    double be  = -av / deg;
    double ak[5], bk[5];
    ak[0] = 1.0; bk[0] = 0.0;
    ak[1] = al;  bk[1] = be;
    for (int k = 2; k < 5; ++k) {
      ak[k] = 2.0 * al * ak[k - 1] - ak[k - 2];
      bk[k] = 2.0 * (be * ak[k - 1] + (al + 64.0 * be) * bk[k - 1]) - bk[k - 2];
    }
    for (int k = 0; k < 5; ++k) { co.a[k] = (float)ak[k]; co.b[k] = (float)bk[k]; }
  }

  const unsigned short* gr1 = (const unsigned short*)(ws + OFF_G1);
  const unsigned short* gr2 = (const unsigned short*)(ws + OFF_G2);
  const unsigned short* gr3 = (const unsigned short*)(ws + OFF_G3);
  float* raw1 = ws + OFF_RAW;
  float* raw2 = raw1 + 256;
  float* raw3 = raw1 + 512;
  float* pp2  = ws + OFF_PP2;
  float* pp   = ws + OFF_PART;
  unsigned short* yv = (unsigned short*)(ws + OFF_Y);

  prep_gran<<<64, 256, 0, stream>>>(W1, W2, W3, ws, co);

  layer_k<256, true ><<<BATCH, 256, 0, stream>>>(x, nullptr, yv, gr1,
                                                 nullptr, nullptr, nullptr, pp);
  finA_k<<<256, 256, 0, stream>>>(pp, pp2);
  finB_k<<<1, 1024, 0, stream>>>(pp2, raw1);
  layer_k<128, false><<<BATCH, 256, 0, stream>>>(nullptr, yv, yv, gr2,
                                                 raw1, g1, b1, pp);
  finA_k<<<256, 256, 0, stream>>>(pp, pp2);
  finB_k<<<1, 1024, 0, stream>>>(pp2, raw2);
  layer_k<128, false><<<BATCH, 256, 0, stream>>>(nullptr, yv, yv, gr3,
                                                 raw2, g2, b2, pp);
  finA_k<<<256, 256, 0, stream>>>(pp, pp2);
  finB_k<<<1, 1024, 0, stream>>>(pp2, raw3);
  pool_k<<<BATCH, 256, 0, stream>>>(yv, raw3, g3, b3, out);

  (void)in_sizes; (void)n_in; (void)out_size; (void)ws_size;
}